// Round 1
// 218.060 us; speedup vs baseline: 1.2590x; 1.2590x over previous
//
#include <hip/hip_runtime.h>

// (B,N,D,K) = (32, 2048, 512, 256)
#define CB 32
#define CN 2048
#define CD 512
#define CK 256

typedef __bf16 bf16x8 __attribute__((ext_vector_type(8)));
typedef float  f32x4  __attribute__((ext_vector_type(4)));

__device__ __forceinline__ unsigned pk2bf(float a, float b) {   // RNE pack: 2 f32 -> bf16x2
    union { float f; unsigned u; } x, y; x.f = a; y.f = b;
    unsigned ru = x.u + 0x7fffu + ((x.u >> 16) & 1u);
    unsigned rv = y.u + 0x7fffu + ((y.u >> 16) & 1u);
    return (ru >> 16) | (rv & 0xffff0000u);
}

__device__ __forceinline__ unsigned short bf16r(float a) {      // RNE f32 -> bf16
    union { float f; unsigned u; } x; x.f = a;
    unsigned r = x.u + 0x7fffu + ((x.u >> 16) & 1u);
    return (unsigned short)(r >> 16);
}

__device__ __forceinline__ void glds16(const void* g, void* l) {
    __builtin_amdgcn_global_load_lds(
        (const __attribute__((address_space(1))) void*)g,
        (__attribute__((address_space(3))) void*)l, 16, 0, 0);
}

// ---------------- K0: prep = {WiT transpose tiles: blocks 0..31} ∪
//                          {vQp partial GEMV: blocks 32..287} ----------------
// Replaces the two 32-block latency-bound kernels with one 288-block launch.
__global__ __launch_bounds__(256) void prep_kernel(
        const float* __restrict__ Wi, const float* __restrict__ Wq,
        const float* __restrict__ vQ, const float* __restrict__ bq,
        unsigned short* __restrict__ WiT, float* __restrict__ vQpP)
{
    const int tid = threadIdx.x;
    if (blockIdx.x < 32) {
        // 64x64 tile transpose Wi[d][k] -> WiT[k][d] (bf16), coalesced both sides
        const int t = blockIdx.x;
        const int d0 = (t >> 2) * 64, k0 = (t & 3) * 64;
        __shared__ float sT[64][68];                 // pad 68: 16B-aligned rows
        const int r = tid >> 4, c4 = (tid & 15) * 4;
        #pragma unroll
        for (int i = 0; i < 4; ++i) {
            float4 v = *reinterpret_cast<const float4*>(
                Wi + (size_t)(d0 + r + i * 16) * CK + k0 + c4);
            *reinterpret_cast<float4*>(&sT[r + i * 16][c4]) = v;
        }
        __syncthreads();
        const int k = tid >> 2, dg = (tid & 3) * 16;
        unsigned short __attribute__((aligned(16))) ov[16];
        #pragma unroll
        for (int j = 0; j < 16; ++j) ov[j] = bf16r(sT[dg + j][k]);
        unsigned short* dst = WiT + (size_t)(k0 + k) * CD + d0 + dg;
        *reinterpret_cast<uint4*>(dst)     = *reinterpret_cast<const uint4*>(&ov[0]);
        *reinterpret_cast<uint4*>(dst + 8) = *reinterpret_cast<const uint4*>(&ov[8]);
    } else {
        // vQpP[b][j][k] = sum_{d in 64-slice j} vQ[b][d]*Wq[d][k]  (+bq at j==0)
        const int bb = blockIdx.x - 32;
        const int b = bb >> 3, j = bb & 7;
        __shared__ float sq[64];
        if (tid < 64) sq[tid] = vQ[b * CD + j * 64 + tid];
        __syncthreads();
        float acc = (j == 0) ? bq[tid] : 0.f;
        const float* wq = Wq + (size_t)j * 64 * CK + tid;
        #pragma unroll
        for (int d = 0; d < 64; d += 8) {
            float wv[8];
            #pragma unroll
            for (int u = 0; u < 8; ++u) wv[u] = wq[(d + u) * CK];   // 8 loads in flight
            #pragma unroll
            for (int u = 0; u < 8; ++u) acc += sq[d + u] * wv[u];
        }
        vQpP[(size_t)bb * CK + tid] = acc;
    }
}

// ---------------- K1: fused scores + online-softmax + K-space num ----------------
// BM=128 rows/block, all K=256 cols, BK=64. grid (16, 32).
// vI is read EXACTLY ONCE; num computed from the MFMA accumulators (vIp) in
// K-space, so no fp32 re-read of vI and no Wi GEMM in finalize.
__global__ __launch_bounds__(256, 2) void scores_fused_kernel(
        const float* __restrict__ vI, const unsigned short* __restrict__ WiT,
        const float* __restrict__ vQpP, const float* __restrict__ Wp,
        float* __restrict__ numP, float* __restrict__ Zp, float* __restrict__ mP)
{
    constexpr int BM = 128, BK = 64, LDA = BK + 8;          // A rows padded: 144 B
    __shared__ __align__(16) unsigned short sA[BM][LDA];    // 18 KB
    __shared__ __align__(16) unsigned short sB[CK * BK];    // 32 KB, swizzled; aliased post-loop
    float* sred = (float*)sB;          // [4][128]
    float* sS   = ((float*)sB) + 512;  // [128] scores (later [0..3] reused for Z partials)
    float* sW   = ((float*)sB) + 640;  // [128] exp weights

    const int tid  = threadIdx.x;
    const int b    = blockIdx.y;
    const int n0   = blockIdx.x * BM;
    const int wave = tid >> 6;
    const int lane = tid & 63;
    const int col  = lane & 15;
    const int quad = lane >> 4;

    const float* vIb = vI + ((size_t)b * CN + n0) * CD;

    // B glds source offsets (swizzled chunk): instr t covers rows wave*64+t*8 .. +8
    int gBoff[8];
    #pragma unroll
    for (int t = 0; t < 8; ++t) {
        int row = wave * 64 + t * 8 + (lane >> 3);
        int c   = (lane & 7) ^ (row & 7);
        gBoff[t] = row * CD + c * 8;    // ushort index; +d0 per chunk
    }

    f32x4 acc[8][4];
    #pragma unroll
    for (int mt = 0; mt < 8; ++mt)
        #pragma unroll
        for (int kt = 0; kt < 4; ++kt)
            acc[mt][kt] = (f32x4){0.f, 0.f, 0.f, 0.f};

    const int ar = tid >> 4;         // A stage row 0..15 (+i*16)
    const int ac = (tid & 15) * 4;   // A stage col (floats)

    for (int d0 = 0; d0 < CD; d0 += BK) {
        __syncthreads();
        // B: async global->LDS, 8 instr/wave, lane-linear LDS, swizzled source
        #pragma unroll
        for (int t = 0; t < 8; ++t)
            glds16(WiT + gBoff[t] + d0, (unsigned short*)sB + (wave * 8 + t) * 512);
        // A: fp32 -> bf16 -> LDS (padded rows)
        #pragma unroll
        for (int i = 0; i < 8; ++i) {
            int r = ar + i * 16;
            float4 v = *reinterpret_cast<const float4*>(vIb + (size_t)r * CD + d0 + ac);
            uint2 p; p.x = pk2bf(v.x, v.y); p.y = pk2bf(v.z, v.w);
            *reinterpret_cast<uint2*>(&sA[r][ac]) = p;
        }
        __syncthreads();
        #pragma unroll
        for (int s = 0; s < 2; ++s) {
            const int dk = s * 32 + quad * 8;
            const int slot = (4 * s + quad) ^ (col & 7);
            bf16x8 af[8], bfr[4];
            #pragma unroll
            for (int mt = 0; mt < 8; ++mt)
                af[mt] = *reinterpret_cast<const bf16x8*>(&sA[mt * 16 + col][dk]);
            #pragma unroll
            for (int kt = 0; kt < 4; ++kt) {
                int R = wave * 64 + kt * 16 + col;
                bfr[kt] = *reinterpret_cast<const bf16x8*>(
                    (unsigned short*)sB + R * 64 + slot * 8);
            }
            #pragma unroll
            for (int mt = 0; mt < 8; ++mt)
                #pragma unroll
                for (int kt = 0; kt < 4; ++kt)
                    acc[mt][kt] = __builtin_amdgcn_mfma_f32_16x16x32_bf16(
                        af[mt], bfr[kt], acc[mt][kt], 0, 0, 0);
        }
    }

    // ---- epilogue 1: per-row scores (vIp never materialized) ----
    float vq[4], wp[4];
    #pragma unroll
    for (int kt = 0; kt < 4; ++kt) {
        int k = wave * 64 + kt * 16 + col;
        float a = 0.f;
        #pragma unroll
        for (int j = 0; j < 8; ++j) a += vQpP[(b * 8 + j) * CK + k];  // combine partials
        vq[kt] = a;
        wp[kt] = Wp[k];
    }
    float sp[8][4];
    #pragma unroll
    for (int mt = 0; mt < 8; ++mt)
        #pragma unroll
        for (int r = 0; r < 4; ++r) {
            float s = 0.f;
            #pragma unroll
            for (int kt = 0; kt < 4; ++kt) {
                float v = acc[mt][kt][r] + vq[kt];
                v = v > 0.f ? v : 0.01f * v;
                s += v * wp[kt];
            }
            sp[mt][r] = s;
        }
    #pragma unroll
    for (int off = 1; off < 16; off <<= 1)
        #pragma unroll
        for (int mt = 0; mt < 8; ++mt)
            #pragma unroll
            for (int r = 0; r < 4; ++r)
                sp[mt][r] += __shfl_xor(sp[mt][r], off);

    __syncthreads();   // all sB ds_reads done; safe to alias
    if (col == 0) {
        #pragma unroll
        for (int mt = 0; mt < 8; ++mt)
            #pragma unroll
            for (int r = 0; r < 4; ++r)
                sred[wave * 128 + mt * 16 + quad * 4 + r] = sp[mt][r];
    }
    __syncthreads();
    if (tid < BM)
        sS[tid] = sred[tid] + sred[128 + tid] + sred[256 + tid] + sred[384 + tid];
    __syncthreads();

    // ---- epilogue 2: block-local softmax pieces ----
    float m = -1e30f;
    #pragma unroll 8
    for (int i = 0; i < BM; ++i) m = fmaxf(m, sS[i]);
    if (tid < BM) sW[tid] = __expf(sS[tid] - m);
    __syncthreads();
    float z = (tid < BM) ? sW[tid] : 0.f;
    #pragma unroll
    for (int off = 32; off > 0; off >>= 1) z += __shfl_xor(z, off);
    if (lane == 0) sS[wave] = z;     // sS scores no longer needed
    __syncthreads();
    const int pidx = b * 16 + blockIdx.x;
    if (tid == 0) {
        Zp[pidx] = sS[0] + sS[1] + sS[2] + sS[3];
        mP[pidx] = m;
    }

    // ---- epilogue 3 (new): K-space num from acc registers, no vI re-read ----
    // lane owns rows {mt*16+quad*4+r}, cols k = wave*64+kt*16+col
    float nk[4] = {0.f, 0.f, 0.f, 0.f};
    #pragma unroll
    for (int mt = 0; mt < 8; ++mt)
        #pragma unroll
        for (int r = 0; r < 4; ++r) {
            float w = sW[mt * 16 + quad * 4 + r];    // LDS broadcast within quad
            #pragma unroll
            for (int kt = 0; kt < 4; ++kt)
                nk[kt] += w * acc[mt][kt][r];
        }
    #pragma unroll
    for (int kt = 0; kt < 4; ++kt) {                 // reduce the 4 quads
        nk[kt] += __shfl_xor(nk[kt], 16);
        nk[kt] += __shfl_xor(nk[kt], 32);
    }
    if (quad == 0) {
        #pragma unroll
        for (int kt = 0; kt < 4; ++kt)
            numP[(size_t)pidx * CK + wave * 64 + kt * 16 + col] = nk[kt];
    }
}

// ---------------- K2: combine partials -> out = num/Z + vQp (elementwise) ----------------
__global__ __launch_bounds__(256) void finalize_kernel(
        const float* __restrict__ numP, const float* __restrict__ Zp,
        const float* __restrict__ mP, const float* __restrict__ vQpP,
        float* __restrict__ out)
{
    const int b = blockIdx.x, tid = threadIdx.x;
    float M = -1e30f;
    #pragma unroll
    for (int j = 0; j < 16; ++j) M = fmaxf(M, mP[b * 16 + j]);
    float w[16]; float Zt = 0.f;
    #pragma unroll
    for (int j = 0; j < 16; ++j) {
        w[j] = __expf(mP[b * 16 + j] - M);
        Zt += w[j] * Zp[b * 16 + j];
    }
    const float inv = 1.f / Zt;
    float s = 0.f;
    #pragma unroll
    for (int j = 0; j < 16; ++j) s += w[j] * numP[(size_t)(b * 16 + j) * CK + tid];
    float vq = 0.f;
    #pragma unroll
    for (int j = 0; j < 8; ++j) vq += vQpP[(size_t)(b * 8 + j) * CK + tid];
    out[b * CK + tid] = s * inv + vq;
}

extern "C" void kernel_launch(void* const* d_in, const int* in_sizes, int n_in,
                              void* d_out, int out_size, void* d_ws, size_t ws_size,
                              hipStream_t stream)
{
    const float* vI = (const float*)d_in[0];   // [B,N,D]
    const float* vQ = (const float*)d_in[1];   // [B,D]
    const float* Wi = (const float*)d_in[2];   // [D,K]
    const float* Wq = (const float*)d_in[3];   // [D,K]
    const float* bq = (const float*)d_in[4];   // [K]
    const float* Wp = (const float*)d_in[5];   // [K,1]
    // d_in[6] = bp: softmax-invariant, unused
    float* out = (float*)d_out;                // [B,K]

    char* ws = (char*)d_ws;
    float*          vQpP = (float*)(ws);                   // 256 KB  [32*8][256]
    unsigned short* WiT  = (unsigned short*)(ws + 262144); // 256 KB  [256][512]
    float*          numP = (float*)(ws + 524288);          // 512 KB  [32*16][256]
    float*          Zp   = (float*)(ws + 524288 + 524288); //   2 KB
    float*          mP   = (float*)(ws + 1048576 + 2048);  //   2 KB

    prep_kernel        <<<288, 256, 0, stream>>>(Wi, Wq, vQ, bq, WiT, vQpP);
    scores_fused_kernel<<<dim3(CN / 128, CB), 256, 0, stream>>>(vI, WiT, vQpP, Wp,
                                                                numP, Zp, mP);
    finalize_kernel    <<<CB, 256, 0, stream>>>(numP, Zp, mP, vQpP, out);
}